// Round 8
// baseline (374.916 us; speedup 1.0000x reference)
//
#include <hip/hip_runtime.h>
#include <hip/hip_fp16.h>

// HungarianMatcher cost C[16,1500,2400] = 5*L1 + focal_class + 2*(-GIoU)
// v7 = v6 with the store stream linearized (q-outer / tile-inner).
// Accounting from v5's profiled run: dur = fill(144us) + kernel + ~52us of
// harness reset dispatches -> v6 kernel ~66us vs ~50us overlapped floor.
// Occupancy 16 vs 24 waves/CU: no effect (v4 vs v6) - latency exonerated.
// Remaining theory: tile-major store order = ~6000 interleaved 4KB write
// streams chip-wide (9.6KB row stride per wave) vs the fill's linear sweep
// at 6.4 TB/s. This version:
//  - holds ALL 3 tiles' targets in registers (48 VGPR tb + 12 laddr,
//    ~110 peak, bound(256,4) cap 128 - no spill, occupancy is sufficient)
//  - loops q OUTER, tile INNER: each block writes its 76.8KB output region
//    in strictly ascending order, 4KB block-wide bursts (fill-like)
//  - plain float4 stores (nt dropped; A/B'd neutral, match fill behavior)
//  - everything else = v6: fp16 [class][q/2] table (24B rows) built once,
//    ds_read_b64 = 4 queries' class cost, corners rematerialized
// Floors: stores 230MB ~37us, VALU ~26us.

namespace {
constexpr int kBS = 16, kQ = 1500, kK = 256, kNT = 150;
constexpr int kT   = kBS * kNT;   // 2400
constexpr int kN   = kBS * kQ;    // 24000
constexpr int kQB  = 8;           // queries per block
constexpr float kAlpha = 0.25f;
constexpr float kEps   = 1e-8f;
}

__global__ __launch_bounds__(256, 4)
void matcher_cost_kernel(const float* __restrict__ logits,   // [N,256]
                         const float* __restrict__ pboxes,   // [N,4] cxcywh
                         const float* __restrict__ tboxes,   // [T,4] cxcywh
                         const int*   __restrict__ tids,     // [T]
                         float* __restrict__ out)            // [N,T]
{
    // [class][q/2] half2, row stride 6 half2 = 24B (cols 4,5 pad). 6 KB.
    __shared__ __align__(16) __half2 s_fcl[kK][6];

    const int tid = threadIdx.x;
    const int n0  = blockIdx.x * kQB;
    const int o4  = tid << 2;
    const bool t2 = o4 < 352;     // tile 2 tail: only threads 0..87 active

    // ---- all 3 tiles' targets -> registers (issued behind table build) ----
    const float4* __restrict__ tb4 = reinterpret_cast<const float4*>(tboxes);
    float4 tb[3][4];
    int laddr[3][4];
#pragma unroll
    for (int t = 0; t < 3; ++t) {
        const int tbase = t * 1024 + o4;
        const bool act  = (t < 2) || t2;
        const int4 ci   = act ? *reinterpret_cast<const int4*>(tids + tbase)
                              : make_int4(0, 0, 0, 0);
        laddr[t][0] = ci.x * 24; laddr[t][1] = ci.y * 24;
        laddr[t][2] = ci.z * 24; laddr[t][3] = ci.w * 24;
#pragma unroll
        for (int e = 0; e < 4; ++e)
            tb[t][e] = act ? tb4[tbase + e] : make_float4(0.f, 0.f, 1.f, 1.f);
    }

    // ---- focal class-cost table (cc + 2.0 folded), thread = class ----
    {
        const float* lrow = logits + (size_t)n0 * kK + tid;
#pragma unroll
        for (int qp = 0; qp < kQB / 2; ++qp) {
            float c[2];
#pragma unroll
            for (int j = 0; j < 2; ++j) {
                const float x   = lrow[(2 * qp + j) * kK];
                const float p   = __builtin_amdgcn_rcpf(1.0f + __expf(-x));
                const float omp = 1.0f - p;
                c[j] = -kAlpha * omp * omp * __logf(p + kEps)
                     + (1.0f - kAlpha) * p * p * __logf(omp + kEps) + 2.0f;
            }
            s_fcl[tid][qp] = __floats2half2_rn(c[0], c[1]);
        }
    }
    __syncthreads();   // the only barrier; LDS read-only below

    const char* __restrict__ fbase = reinterpret_cast<const char*>(s_fcl);
    float* __restrict__ ob = out + (size_t)n0 * kT;

#pragma unroll
    for (int qg = 0; qg < kQB / 4; ++qg) {
        // class costs for 4 queries x all 12 held targets (one b64 each)
        uint2 ccr[3][4];
#pragma unroll
        for (int t = 0; t < 3; ++t)
#pragma unroll
            for (int e = 0; e < 4; ++e)
                ccr[t][e] = *reinterpret_cast<const uint2*>(
                                fbase + laddr[t][e] + qg * 8);

#pragma unroll
        for (int qi = 0; qi < 4; ++qi) {
            const int q = qg * 4 + qi;
            const float4 pb = *reinterpret_cast<const float4*>(
                                  pboxes + (size_t)(n0 + q) * 4);
            const float pcx = pb.x, pcy = pb.y, pw = pb.z, ph = pb.w;
            const float px1 = fmaf(-0.5f, pw, pcx), px2 = fmaf(0.5f, pw, pcx);
            const float py1 = fmaf(-0.5f, ph, pcy), py2 = fmaf(0.5f, ph, pcy);
            const float parea = pw * ph;

            // tile-inner: stores ascend 0 -> 9.6KB within row q, rows ascend
#pragma unroll
            for (int t = 0; t < 3; ++t) {
                if (t == 2 && !t2) continue;
                float4 res; float* rp = &res.x;
#pragma unroll
                for (int e = 0; e < 4; ++e) {
                    const unsigned u  = (qi < 2) ? ccr[t][e].x : ccr[t][e].y;
                    const __half2 h2  = *reinterpret_cast<const __half2*>(&u);
                    const float   cc  = (qi & 1) ? __high2float(h2)
                                                 : __low2float(h2);
                    const float bcx = tb[t][e].x, bcy = tb[t][e].y;
                    const float bw  = tb[t][e].z, bh  = tb[t][e].w;
                    // L1 cost (cxcywh space)
                    const float cb = fabsf(pcx - bcx) + fabsf(pcy - bcy)
                                   + fabsf(pw - bw)  + fabsf(ph - bh);
                    // corners rematerialized (fma cheaper than VGPR)
                    const float bx1 = fmaf(-0.5f, bw, bcx), bx2 = fmaf(0.5f, bw, bcx);
                    const float by1 = fmaf(-0.5f, bh, bcy), by2 = fmaf(0.5f, bh, bcy);
                    // overlap; enclose via identity ew = pw+bw-ow
                    const float ow = fminf(px2, bx2) - fmaxf(px1, bx1);
                    const float oh = fminf(py2, by2) - fmaxf(py1, by1);
                    const float iw = fmaxf(ow, 0.0f), ih = fmaxf(oh, 0.0f);
                    const float ew = (pw + bw) - ow, eh = (ph + bh) - oh;
                    const float inter = iw * ih;
                    const float uni   = fmaf(bw, bh, parea) - inter;
                    const float ear   = ew * eh;
                    // out = 5cb + (cc+2) - 2*(inter*ear + uni*uni)/(uni*ear)
                    const float rr   = __builtin_amdgcn_rcpf(uni * ear);
                    const float frac = fmaf(uni, uni, inter * ear) * rr;
                    rp[e] = fmaf(-2.0f, frac, fmaf(5.0f, cb, cc));
                }
                *reinterpret_cast<float4*>(ob + (size_t)q * kT + t * 1024 + o4) = res;
            }
        }
    }
}

extern "C" void kernel_launch(void* const* d_in, const int* in_sizes, int n_in,
                              void* d_out, int out_size, void* d_ws, size_t ws_size,
                              hipStream_t stream) {
    const float* logits = (const float*)d_in[0];   // [16,1500,256]
    const float* pboxes = (const float*)d_in[1];   // [16,1500,4]
    const float* tboxes = (const float*)d_in[2];   // [2400,4]
    const int*   tids   = (const int*)d_in[3];     // [2400]
    float* out = (float*)d_out;                    // [16,1500,2400] fp32

    dim3 grid(kN / kQB);   // 3000 blocks
    dim3 block(256);
    hipLaunchKernelGGL(matcher_cost_kernel, grid, block, 0, stream,
                       logits, pboxes, tboxes, tids, out);
}

// Round 9
// 290.869 us; speedup vs baseline: 1.2890x; 1.2890x over previous
//
#include <hip/hip_runtime.h>
#include <hip/hip_fp16.h>

// HungarianMatcher cost C[16,1500,2400] = 5*L1 + focal_class + 2*(-GIoU)
// v8: q-outer/tile-inner store linearization, register-safe (v7 spilled:
// 478MB writes = 230 output + 248 scratch; allocator spills, never remats).
//  - kQB=4: ALL 4 queries' class costs per target = ONE 8B LDS read ->
//    ccr[3][4] loaded once, total persistent state ~100 VGPR
//  - __launch_bounds__(256) with NO min-waves: no VGPR cap -> no forced
//    spill (v4/v6 proved occupancy 16 vs 24 waves/CU is a non-factor)
//  - q outer, tile inner: block writes its 4-row x 9.6KB output region in
//    strictly ascending address order (fill-like 4KB block-wide bursts)
//  - s_fcl[256][3] half2: 12B rows (stride-3 dwords coprime with 32 banks:
//    writes conflict-free, random-cid gathers ~2-way = free per m136)
//  - targets held in registers for all 3 tiles (48 VGPR), corners remat'd
// Floors: stores 230MB ~37us, VALU ~26us. v6 kernel ~66us; testing whether
// store-stream order recovers toward ~55us. Clean-counters + dur>=262 =>
// store ordering null => roofline.

namespace {
constexpr int kBS = 16, kQ = 1500, kK = 256, kNT = 150;
constexpr int kT   = kBS * kNT;   // 2400
constexpr int kN   = kBS * kQ;    // 24000
constexpr int kQB  = 4;           // queries per block (one b64 = all 4 cc)
constexpr float kAlpha = 0.25f;
constexpr float kEps   = 1e-8f;
}

__global__ __launch_bounds__(256)
void matcher_cost_kernel(const float* __restrict__ logits,   // [N,256]
                         const float* __restrict__ pboxes,   // [N,4] cxcywh
                         const float* __restrict__ tboxes,   // [T,4] cxcywh
                         const int*   __restrict__ tids,     // [T]
                         float* __restrict__ out)            // [N,T]
{
    // [class][3] half2: cols 0-1 = cc(q0..q3)+2, col 2 pad. 3 KB.
    __shared__ __half2 s_fcl[kK][3];

    const int tid = threadIdx.x;
    const int n0  = blockIdx.x * kQB;
    const int o4  = tid << 2;
    const bool t2 = o4 < 352;     // tile-2 tail: threads 0..87 only

    // ---- all 3 tiles' targets -> registers (issued before table build) ----
    const float4* __restrict__ tb4 = reinterpret_cast<const float4*>(tboxes);
    float4 tb[3][4];
    int lad[3][4];
#pragma unroll
    for (int t = 0; t < 3; ++t) {
        const int tbase = t * 1024 + o4;
        const bool act  = (t < 2) || t2;
        const int4 ci   = act ? *reinterpret_cast<const int4*>(tids + tbase)
                              : make_int4(0, 0, 0, 0);
        lad[t][0] = ci.x * 12; lad[t][1] = ci.y * 12;
        lad[t][2] = ci.z * 12; lad[t][3] = ci.w * 12;
#pragma unroll
        for (int e = 0; e < 4; ++e)
            tb[t][e] = act ? tb4[tbase + e] : make_float4(0.f, 0.f, 1.f, 1.f);
    }

    // ---- focal class-cost table (cc + 2.0 folded), thread = class ----
    {
        const float* lrow = logits + (size_t)n0 * kK + tid;
        float c[kQB];
#pragma unroll
        for (int j = 0; j < kQB; ++j) {
            const float x   = lrow[j * kK];
            const float p   = __builtin_amdgcn_rcpf(1.0f + __expf(-x));
            const float omp = 1.0f - p;
            c[j] = -kAlpha * omp * omp * __logf(p + kEps)
                 + (1.0f - kAlpha) * p * p * __logf(omp + kEps) + 2.0f;
        }
        s_fcl[tid][0] = __floats2half2_rn(c[0], c[1]);
        s_fcl[tid][1] = __floats2half2_rn(c[2], c[3]);
    }
    __syncthreads();   // the only barrier; LDS read-only below

    // ---- one-time gather: 4-query class costs for all 12 held targets ----
    // dword-pair loads (4B-aligned rows; compiler merges to ds_read2_b32)
    const char* __restrict__ fbase = reinterpret_cast<const char*>(s_fcl);
    uint2 ccr[3][4];
#pragma unroll
    for (int t = 0; t < 3; ++t)
#pragma unroll
        for (int e = 0; e < 4; ++e) {
            const unsigned* fp =
                reinterpret_cast<const unsigned*>(fbase + lad[t][e]);
            ccr[t][e].x = fp[0];
            ccr[t][e].y = fp[1];
        }

    float* __restrict__ ob = out + (size_t)n0 * kT;

#pragma unroll
    for (int q = 0; q < kQB; ++q) {       // q outer: rows ascend
        const float4 pb = *reinterpret_cast<const float4*>(
                              pboxes + (size_t)(n0 + q) * 4);
        const float pcx = pb.x, pcy = pb.y, pw = pb.z, ph = pb.w;
        const float px1 = fmaf(-0.5f, pw, pcx), px2 = fmaf(0.5f, pw, pcx);
        const float py1 = fmaf(-0.5f, ph, pcy), py2 = fmaf(0.5f, ph, pcy);
        const float parea = pw * ph;

#pragma unroll
        for (int t = 0; t < 3; ++t) {     // tile inner: cols ascend in row
            if (t == 2 && !t2) continue;
            float4 res; float* rp = &res.x;
#pragma unroll
            for (int e = 0; e < 4; ++e) {
                const unsigned u  = (q < 2) ? ccr[t][e].x : ccr[t][e].y;
                const __half2 h2  = *reinterpret_cast<const __half2*>(&u);
                const float   cc  = (q & 1) ? __high2float(h2)
                                            : __low2float(h2);
                const float bcx = tb[t][e].x, bcy = tb[t][e].y;
                const float bw  = tb[t][e].z, bh  = tb[t][e].w;
                // L1 cost (cxcywh space)
                const float cb = fabsf(pcx - bcx) + fabsf(pcy - bcy)
                               + fabsf(pw - bw)  + fabsf(ph - bh);
                // corners rematerialized (fma cheaper than VGPR)
                const float bx1 = fmaf(-0.5f, bw, bcx), bx2 = fmaf(0.5f, bw, bcx);
                const float by1 = fmaf(-0.5f, bh, bcy), by2 = fmaf(0.5f, bh, bcy);
                // overlap; enclose via identity ew = pw+bw-ow
                const float ow = fminf(px2, bx2) - fmaxf(px1, bx1);
                const float oh = fminf(py2, by2) - fmaxf(py1, by1);
                const float iw = fmaxf(ow, 0.0f), ih = fmaxf(oh, 0.0f);
                const float ew = (pw + bw) - ow, eh = (ph + bh) - oh;
                const float inter = iw * ih;
                const float uni   = fmaf(bw, bh, parea) - inter;
                const float ear   = ew * eh;
                // out = 5cb + (cc+2) - 2*(inter*ear + uni*uni)/(uni*ear)
                const float rr   = __builtin_amdgcn_rcpf(uni * ear);
                const float frac = fmaf(uni, uni, inter * ear) * rr;
                rp[e] = fmaf(-2.0f, frac, fmaf(5.0f, cb, cc));
            }
            *reinterpret_cast<float4*>(ob + (size_t)q * kT + t * 1024 + o4) = res;
        }
    }
}

extern "C" void kernel_launch(void* const* d_in, const int* in_sizes, int n_in,
                              void* d_out, int out_size, void* d_ws, size_t ws_size,
                              hipStream_t stream) {
    const float* logits = (const float*)d_in[0];   // [16,1500,256]
    const float* pboxes = (const float*)d_in[1];   // [16,1500,4]
    const float* tboxes = (const float*)d_in[2];   // [2400,4]
    const int*   tids   = (const int*)d_in[3];     // [2400]
    float* out = (float*)d_out;                    // [16,1500,2400] fp32

    dim3 grid(kN / kQB);   // 6000 blocks
    dim3 block(256);
    hipLaunchKernelGGL(matcher_cost_kernel, grid, block, 0, stream,
                       logits, pboxes, tboxes, tids, out);
}